// Round 16
// baseline (162.516 us; speedup 1.0000x reference)
//
#include <hip/hip_runtime.h>

// Path signature M=4, d=10, L=256, B=2048 — MFMA formulation, round 16.
// Same GEMM math as r11/r14/r15 (absmax 13), now with the sequential S2 scan
// SPLIT IN HALF across waves + a rank-1 correction chunk:
//   half 0: t in [0,128)  — true S2 prefix (Ds from 0)
//   half 1: t in [128,255) — local scan from 0; missing S2_128 term is rank-1:
//     dC[ij,n] = S2_128[ij] * (sum_{t>=128}(u_t+0.5w_t))[n]   (cells)
//              = S2_128[ij] * (x_255-x_128)[k]                 (v-cols, S3)
//   -> one extra K=32 chunk: P=[S2hi,S2lo,S2hi,0], Q=[ghi,ghi,glo,0] (keeps
//      hi*lo cross terms; dropped lo*lo ~ 2^-18 rel).
// 512 threads: waves 0-1 pairs h0, 2-3 pairs h1, 4-5 Q h0, 6-7 Q h1 (balanced
// producer load, straggler halves); 49 MFMA tiles spread over 8 waves (<=8 ea).
// Slot-major [slot][112 rows][16B], double-buffered, 1 barrier/chunk.

#define SIG 11110

typedef short bf16x8 __attribute__((ext_vector_type(8)));
typedef float f32x4  __attribute__((ext_vector_type(4)));

__device__ __forceinline__ unsigned cvt_pk2(float lo, float hi) {
    unsigned r;
    asm("v_cvt_pk_bf16_f32 %0, %1, %2" : "=v"(r) : "v"(lo), "v"(hi));
    return r;
}
__device__ __forceinline__ float trunc_bf(float a) {
    return __uint_as_float(__float_as_uint(a) & 0xFFFF0000u);
}
// (bf16_hi(a) | bf16(a - hi)<<16), hi = truncated-to-bf16 (exact residual)
__device__ __forceinline__ unsigned split_pack(float a) {
    const float hi = trunc_bf(a);
    return cvt_pk2(hi, a - hi);
}

template<int MI, int NI>
__device__ __forceinline__ void consume(const unsigned* __restrict__ Pb,
                                        const unsigned* __restrict__ Qb,
                                        int r0, int c0, int lane,
                                        f32x4 (&acc)[2][4]) {
    const int slot = lane >> 4, rr = lane & 15;
    bf16x8 Bf[NI];
    #pragma unroll
    for (int ni = 0; ni < NI; ++ni)
        Bf[ni] = *(const bf16x8*)(Qb + slot * 448 + (c0 + ni * 16 + rr) * 4);
    #pragma unroll
    for (int mi = 0; mi < MI; ++mi) {
        const bf16x8 Af = *(const bf16x8*)(Pb + slot * 448 + (r0 + mi * 16 + rr) * 4);
        #pragma unroll
        for (int ni = 0; ni < NI; ++ni)
            acc[mi][ni] = __builtin_amdgcn_mfma_f32_16x16x32_bf16(Af, Bf[ni], acc[mi][ni], 0, 0, 0);
    }
}

__global__ __launch_bounds__(512, 4)
void sig_mfma9(const float* __restrict__ xg, float* __restrict__ out) {
    __shared__ float    xs[2560];          // path [t*10+dim]           10240 B
    __shared__ unsigned Pl[2][4 * 448];    // dbuf [slot][112 rows][4w] 14336 B
    __shared__ unsigned Ql[2][4 * 448];    //                           14336 B
    __shared__ float    s2h1[100];         // half-1 partial S2          400 B

    const int tid  = threadIdx.x;
    const int b    = blockIdx.x;
    const int lane = tid & 63;
    const int wv   = tid >> 6;
    const float* __restrict__ xb = xg + (size_t)b * 2560;

    // stage path (coalesced) + zero pads (P rows 100..111, Q rows 110..111; both bufs)
    #pragma unroll
    for (int r = 0; r < 5; ++r) xs[r * 512 + tid] = xb[r * 512 + tid];
    if (tid < 384) {
        const int buf = tid / 192, r = tid % 192, slot = r / 48, rem = r % 48;
        Pl[buf][slot * 448 + (100 + rem / 4) * 4 + (rem & 3)] = 0u;
    }
    if (tid < 64) {
        const int buf = tid / 32, r = tid % 32, slot = r / 8, rem = r % 8;
        Ql[buf][slot * 448 + (110 + rem / 4) * 4 + (rem & 3)] = 0u;
    }
    __syncthreads();   // staging visible before any xs read (r12/r13 lesson)

    // roles: grp 0 = pairs h0, 1 = pairs h1, 2 = Q h0, 3 = Q h1
    const int  grp    = tid >> 7;
    const int  sub    = tid & 127;
    const bool isPair = (grp < 2) && (sub < 100);
    const bool isQrow = (grp >= 2) && (sub < 110);
    const bool isCell = isQrow && (sub < 100);
    const bool isVcol = isQrow && (sub >= 100);
    const int  h      = grp & 1;
    const int  row    = sub;

    int i1 = 0, i2 = 0;
    if (isPair || isCell) { i1 = row / 10; i2 = row - i1 * 10; }
    else if (isVcol)      { i1 = row - 100; i2 = i1; }

    const int xoff = h * 1280;
    float c1 = xs[xoff + i1], c2 = xs[xoff + i2];   // chains x_t[i1], x_t[i2]
    const float x0i = xs[i1];                        // S1 ref: path start
    const float xL2 = xs[2550 + i2];                 // cells: x_L[l]
    float Ds   = 0.f;                                // pairs: local S2 scan
    float gacc = 0.f;                                // h1 cells: sum(u + 0.5w)

    f32x4 acc[2][4];
    #pragma unroll
    for (int mi = 0; mi < 2; ++mi)
        #pragma unroll
        for (int ni = 0; ni < 4; ++ni) acc[mi][ni] = (f32x4){0.f, 0.f, 0.f, 0.f};

    auto produce = [&](int ch, unsigned* Pb, unsigned* Qb) {
        if (isPair) {
            unsigned q0 = 0, q1 = 0;
            #pragma unroll
            for (int tl = 0; tl < 4; ++tl) {
                const int  t     = h * 128 + ch * 4 + tl;
                const bool valid = (t < 255);        // false only at h1,ch31,tl3
                const int  tt    = valid ? t : 254;
                const float n1 = xs[(tt + 1) * 10 + i1];
                const float n2 = xs[(tt + 1) * 10 + i2];
                const float vi = n1 - c1, vj = n2 - c2;
                const float s1f  = c1 - x0i;
                const float vivj = vi * vj;
                const float t1   = s1f * vj;
                float a  = fmaf(vivj, 1.f/6.f,  fmaf(t1, 0.5f,    Ds));
                float bb = fmaf(vivj, 1.f/24.f, fmaf(t1, 1.f/6.f, 0.5f * Ds));
                if (!valid) { a = 0.f; bb = 0.f; }
                const unsigned pa = split_pack(a), pb = split_pack(bb);
                if (valid) { Ds += fmaf(0.5f, vivj, t1); c1 = n1; c2 = n2; }
                if ((tl & 1) == 0) { q0 = pa; q1 = pb; }
                else *(uint4*)&Pb[(2 * h + (tl >> 1)) * 448 + row * 4] = make_uint4(q0, q1, pa, pb);
            }
        } else if (isCell) {
            unsigned q0 = 0, q1 = 0;
            #pragma unroll
            for (int tl = 0; tl < 4; ++tl) {
                const int  t     = h * 128 + ch * 4 + tl;
                const bool valid = (t < 255);
                const int  tt    = valid ? t : 254;
                const float n1 = xs[(tt + 1) * 10 + i1];
                const float n2 = xs[(tt + 1) * 10 + i2];
                const float vk = n1 - c1, vl = n2 - c2;
                float u = vk * (xL2 - n2);
                float w = vk * vl;
                if (!valid) { u = 0.f; w = 0.f; }
                const unsigned pu = cvt_pk2(u, u), pw = cvt_pk2(w, w);
                if (valid) { c1 = n1; c2 = n2; gacc += fmaf(0.5f, w, u); }
                if ((tl & 1) == 0) { q0 = pu; q1 = pw; }
                else *(uint4*)&Qb[(2 * h + (tl >> 1)) * 448 + row * 4] = make_uint4(q0, q1, pu, pw);
            }
        } else if (isVcol) {
            unsigned q0 = 0;
            #pragma unroll
            for (int tl = 0; tl < 4; ++tl) {
                const int  t     = h * 128 + ch * 4 + tl;
                const bool valid = (t < 255);
                const int  tt    = valid ? t : 254;
                const float n1 = xs[(tt + 1) * 10 + i1];
                float v = n1 - c1;
                if (!valid) v = 0.f;
                const unsigned pv = cvt_pk2(v, v);
                if (valid) c1 = n1;
                if ((tl & 1) == 0) q0 = pv;
                else *(uint4*)&Qb[(2 * h + (tl >> 1)) * 448 + row * 4] = make_uint4(q0, 0u, pv, 0u);
            }
        }
    };

    // 49 tiles over 8 waves (<=8 MFMA each); heavy tiles on light (Q) waves.
    // Out-of-range acc entries stay zero and self-guard in the epilogue (m/n>=112).
    auto mfma_all = [&](const unsigned* Pb, const unsigned* Qb) {
        switch (wv) {
        case 0:  consume<1, 3>(Pb, Qb, 96, 64, lane, acc); break;   // 3
        case 1:  consume<1, 4>(Pb, Qb, 96,  0, lane, acc); break;   // 4
        case 2:  consume<2, 3>(Pb, Qb, 64, 64, lane, acc); break;   // 6
        case 3:  consume<2, 3>(Pb, Qb, 32, 64, lane, acc); break;   // 6
        case 4:  consume<2, 4>(Pb, Qb,  0,  0, lane, acc); break;   // 8
        case 5:  consume<2, 4>(Pb, Qb, 32,  0, lane, acc); break;   // 8
        case 6:  consume<2, 4>(Pb, Qb, 64,  0, lane, acc); break;   // 8
        default: consume<2, 3>(Pb, Qb,  0, 64, lane, acc); break;   // 6
        }
    };

    produce(0, Pl[0], Ql[0]);
    __syncthreads();

    for (int ch = 0; ch < 32; ++ch) {
        mfma_all(Pl[ch & 1], Ql[ch & 1]);
        if (ch < 31) produce(ch + 1, Pl[(ch + 1) & 1], Ql[(ch + 1) & 1]);
        __syncthreads();
    }

    // ---- rank-1 S2_128 correction chunk (buf 0 is free after the loop) ----
    for (int e = tid; e < 1792; e += 512) { Pl[0][e] = 0u; Ql[0][e] = 0u; }
    if (isPair && h == 1) s2h1[row] = Ds;
    __syncthreads();
    if (isPair && h == 0) {
        const float hi = trunc_bf(Ds);                 // S2_128 = half-0 final Ds
        Pl[0][row * 4 + 0] = cvt_pk2(hi, Ds - hi);     // K0=S2hi, K1=S2lo
        Pl[0][row * 4 + 1] = cvt_pk2(hi, 0.f);         // K2=S2hi
    }
    if (isQrow && h == 1) {
        const float g   = isVcol ? (xs[2550 + i1] - xs[1280 + i1]) : gacc;
        const float ghi = trunc_bf(g);
        Ql[0][row * 4 + 0] = cvt_pk2(ghi, ghi);        // K0,K1 = ghi
        Ql[0][row * 4 + 1] = cvt_pk2(g - ghi, 0.f);    // K2 = glo
    }
    __syncthreads();
    mfma_all(Pl[0], Ql[0]);

    // ---- epilogue: [S1(10) | S2(100) | S3(1000) | S4(10000)] ----
    const size_t base = (size_t)b * SIG;
    if (tid < 10) out[base + tid] = xs[2550 + tid] - xs[tid];        // S1 exact
    if (isPair && h == 0) out[base + 10 + row] = Ds + s2h1[row];     // S2 exact

    int r0, c0;
    switch (wv) {
    case 0:  r0 = 96; c0 = 64; break;
    case 1:  r0 = 96; c0 =  0; break;
    case 2:  r0 = 64; c0 = 64; break;
    case 3:  r0 = 32; c0 = 64; break;
    case 4:  r0 =  0; c0 =  0; break;
    case 5:  r0 = 32; c0 =  0; break;
    case 6:  r0 = 64; c0 =  0; break;
    default: r0 =  0; c0 = 64; break;
    }
    #pragma unroll
    for (int mi = 0; mi < 2; ++mi) {
        #pragma unroll
        for (int ni = 0; ni < 4; ++ni) {
            #pragma unroll
            for (int r = 0; r < 4; ++r) {
                const int m = r0 + mi * 16 + (lane >> 4) * 4 + r;
                const int n = c0 + ni * 16 + (lane & 15);
                if (m < 100) {
                    if (n < 100)      out[base + 1110 + m * 100 + n]         = acc[mi][ni][r];
                    else if (n < 110) out[base + 110  + m * 10  + (n - 100)] = acc[mi][ni][r];
                }
            }
        }
    }
}

extern "C" void kernel_launch(void* const* d_in, const int* in_sizes, int n_in,
                              void* d_out, int out_size, void* d_ws, size_t ws_size,
                              hipStream_t stream) {
    const float* x = (const float*)d_in[0];
    float* out = (float*)d_out;
    const int B = in_sizes[0] / 2560;   // 2048 batches, one block each
    sig_mfma9<<<B, 512, 0, stream>>>(x, out);
}

// Round 17
// 118.976 us; speedup vs baseline: 1.3660x; 1.3660x over previous
//
#include <hip/hip_runtime.h>

// Path signature M=4, d=10, L=256, B=2048 — MFMA formulation, round 17.
// b-row ELIMINATED via b = a/2 - r1/24 - r2/12 (r1=vivj, r2=S1vj):
//   per-t contribution: a*(u+w/2) + r1*(-w/24) + r2*(-w/12);  S3 = sum a*v_k.
// K-rows per t: P=[a_hi,a_lo,r1,r2], Q_cell=[uw,uw,-w/24,-w/12], Q_vcol=[v,v,0,0].
// Error structure identical to r11 (absmax 13): scan-side a split hi/lo; plain
// bf16 only on small v-products. Pair lanes 17->12 VALU/t (ONE split_pack),
// cells 7->10 — all 4 producer SIMDs balanced. MFMA tiles re-weighted: pair
// waves (light producers) now take 16+12, cell waves 12+9.
// Structure = r15: dbuf P/Q slot-major [slot][112][16B], 1 barrier/chunk,
// produce_t<8>/<7> tail split, staging barrier before chain init (r12/13 bug).

#define SIG 11110

typedef short bf16x8 __attribute__((ext_vector_type(8)));
typedef float f32x4  __attribute__((ext_vector_type(4)));

__device__ __forceinline__ unsigned cvt_pk2(float lo, float hi) {
    unsigned r;
    asm("v_cvt_pk_bf16_f32 %0, %1, %2" : "=v"(r) : "v"(lo), "v"(hi));
    return r;
}
// (bf16_hi(a) | bf16(a - hi)<<16), hi = truncated-to-bf16 (exact residual)
__device__ __forceinline__ unsigned split_pack(float a) {
    const float hi = __uint_as_float(__float_as_uint(a) & 0xFFFF0000u);
    return cvt_pk2(hi, a - hi);
}

template<int MI, int NI>
__device__ __forceinline__ void consume(const unsigned* __restrict__ Pb,
                                        const unsigned* __restrict__ Qb,
                                        int r0, int c0, int lane,
                                        f32x4 (&acc)[4][4]) {
    const int slot = lane >> 4, rr = lane & 15;
    bf16x8 Bf[NI];
    #pragma unroll
    for (int ni = 0; ni < NI; ++ni)
        Bf[ni] = *(const bf16x8*)(Qb + slot * 448 + (c0 + ni * 16 + rr) * 4);
    #pragma unroll
    for (int mi = 0; mi < MI; ++mi) {
        const bf16x8 Af = *(const bf16x8*)(Pb + slot * 448 + (r0 + mi * 16 + rr) * 4);
        #pragma unroll
        for (int ni = 0; ni < NI; ++ni)
            acc[mi][ni] = __builtin_amdgcn_mfma_f32_16x16x32_bf16(Af, Bf[ni], acc[mi][ni], 0, 0, 0);
    }
}

// NV = valid t's in this chunk (8 for chunks 0..30, 7 for chunk 31).
template<int NV>
__device__ __forceinline__ void produce_t(int ch, const float* __restrict__ xs,
                                          unsigned* __restrict__ Pb,
                                          unsigned* __restrict__ Qb,
                                          bool isPair, bool isCell, bool isVcol,
                                          int tid, int qrow, int i1, int i2,
                                          float x0i, float xL2,
                                          float& c1, float& c2, float& Ds) {
    if (isPair) {
        unsigned q0 = 0, q1 = 0;
        #pragma unroll
        for (int tl = 0; tl < 8; ++tl) {
            unsigned pa, pr;
            if (tl < NV) {
                const float n1 = xs[(ch * 8 + tl + 1) * 10 + i1];
                const float n2 = xs[(ch * 8 + tl + 1) * 10 + i2];
                const float vi = n1 - c1, vj = n2 - c2;
                const float s1f = c1 - x0i;
                const float r1  = vi * vj;
                const float r2  = s1f * vj;
                const float a   = fmaf(r1, 1.f/6.f, fmaf(r2, 0.5f, Ds));
                pa = split_pack(a);
                pr = cvt_pk2(r1, r2);
                Ds += fmaf(0.5f, r1, r2);        // dS2 = vivj/2 + S1*vj
                c1 = n1; c2 = n2;
            } else { pa = 0u; pr = 0u; }
            if ((tl & 1) == 0) { q0 = pa; q1 = pr; }
            else *(uint4*)&Pb[(tl >> 1) * 448 + tid * 4] = make_uint4(q0, q1, pa, pr);
        }
    } else if (isCell) {
        unsigned q0 = 0, q1 = 0;
        #pragma unroll
        for (int tl = 0; tl < 8; ++tl) {
            unsigned pu, pw;
            if (tl < NV) {
                const float n1 = xs[(ch * 8 + tl + 1) * 10 + i1];
                const float n2 = xs[(ch * 8 + tl + 1) * 10 + i2];
                const float vk = n1 - c1, vl = n2 - c2;
                const float w  = vk * vl;
                const float m2 = fmaf(-0.5f, c2 + n2, xL2);   // R + v/2 factor
                const float uw = vk * m2;                     // u + w/2
                pu = cvt_pk2(uw, uw);
                pw = cvt_pk2(w * (-1.f/24.f), w * (-1.f/12.f));
                c1 = n1; c2 = n2;
            } else { pu = 0u; pw = 0u; }
            if ((tl & 1) == 0) { q0 = pu; q1 = pw; }
            else *(uint4*)&Qb[(tl >> 1) * 448 + qrow * 4] = make_uint4(q0, q1, pu, pw);
        }
    } else if (isVcol) {
        unsigned q0 = 0;
        #pragma unroll
        for (int tl = 0; tl < 8; ++tl) {
            unsigned pv;
            if (tl < NV) {
                const float n1 = xs[(ch * 8 + tl + 1) * 10 + i1];
                pv = cvt_pk2(n1 - c1, n1 - c1);
                c1 = n1;
            } else pv = 0u;
            if ((tl & 1) == 0) q0 = pv;
            else *(uint4*)&Qb[(tl >> 1) * 448 + qrow * 4] = make_uint4(q0, 0u, pv, 0u);
        }
    }
}

__global__ __launch_bounds__(256, 3)
void sig_mfma10(const float* __restrict__ xg, float* __restrict__ out) {
    __shared__ float    xs[2560];          // path [t*10+dim]           10240 B
    __shared__ unsigned Pl[2][4 * 448];    // dbuf [slot][112 rows][4w] 14336 B
    __shared__ unsigned Ql[2][4 * 448];    //                           14336 B

    const int tid  = threadIdx.x;
    const int b    = blockIdx.x;
    const int lane = tid & 63;
    const int wv   = tid >> 6;
    const float* __restrict__ xb = xg + (size_t)b * 2560;

    // stage path (coalesced) + zero pads (P rows 100..111, Q rows 110..111; both bufs)
    #pragma unroll
    for (int r = 0; r < 10; ++r) xs[r * 256 + tid] = xb[r * 256 + tid];
    for (int e = tid; e < 384; e += 256) {
        const int buf = e / 192, r = e % 192, slot = r / 48, rem = r % 48;
        Pl[buf][slot * 448 + (100 + rem / 4) * 4 + (rem & 3)] = 0u;
    }
    if (tid < 64) {
        const int buf = tid / 32, r = tid % 32, slot = r / 8, rem = r % 8;
        Ql[buf][slot * 448 + (110 + rem / 4) * 4 + (rem & 3)] = 0u;
    }
    __syncthreads();   // staging visible BEFORE any xs read (r12/r13 lesson)

    // roles: waves 0-1 = pair scan -> P ; waves 2-3 = closed-form -> Q
    const bool isPair = (tid < 100);
    const int  qrow   = tid - 128;
    const bool isCell = (qrow >= 0) && (qrow < 100);
    const bool isVcol = (qrow >= 100) && (qrow < 110);

    int i1 = 0, i2 = 0;
    if (isPair)      { i1 = tid / 10;  i2 = tid - i1 * 10; }
    else if (isCell) { i1 = qrow / 10; i2 = qrow - i1 * 10; }
    else if (isVcol) { i1 = qrow - 100; i2 = i1; }

    float c1 = xs[i1], c2 = xs[i2];             // chains x_t[i1], x_t[i2]
    const float x0i = c1;
    const float xL2 = xs[2550 + i2];            // cells: x_L[l]
    float Ds = 0.f;                             // pairs: running S2 (exact f32)

    f32x4 acc[4][4];
    #pragma unroll
    for (int mi = 0; mi < 4; ++mi)
        #pragma unroll
        for (int ni = 0; ni < 4; ++ni) acc[mi][ni] = (f32x4){0.f, 0.f, 0.f, 0.f};

    produce_t<8>(0, xs, Pl[0], Ql[0], isPair, isCell, isVcol,
                 tid, qrow, i1, i2, x0i, xL2, c1, c2, Ds);
    __syncthreads();

    for (int ch = 0; ch < 32; ++ch) {
        const unsigned* Pb = Pl[ch & 1];
        const unsigned* Qb = Ql[ch & 1];
        // pair waves (light producers) take the heavy tile quadrants
        if      (wv == 0) consume<4, 4>(Pb, Qb,  0,  0, lane, acc);   // 16
        else if (wv == 1) consume<4, 3>(Pb, Qb,  0, 64, lane, acc);   // 12
        else if (wv == 2) consume<3, 4>(Pb, Qb, 64,  0, lane, acc);   // 12
        else              consume<3, 3>(Pb, Qb, 64, 64, lane, acc);   //  9
        if (ch < 30)
            produce_t<8>(ch + 1, xs, Pl[(ch + 1) & 1], Ql[(ch + 1) & 1],
                         isPair, isCell, isVcol, tid, qrow, i1, i2, x0i, xL2, c1, c2, Ds);
        else if (ch == 30)
            produce_t<7>(31, xs, Pl[1], Ql[1],
                         isPair, isCell, isVcol, tid, qrow, i1, i2, x0i, xL2, c1, c2, Ds);
        __syncthreads();   // one barrier/chunk: separates read@ch from write@ch+2
    }

    // epilogue: [S1(10) | S2(100) | S3(1000) | S4(10000)]
    const size_t base = (size_t)b * SIG;
    if (tid < 10)  out[base + tid] = xs[2550 + tid] - xs[tid];   // S1 exact
    if (isPair)    out[base + 10 + tid] = Ds;                    // S2 exact

    const int r0 = (wv < 2) ? 0 : 64;
    const int c0 = (wv == 0 || wv == 2) ? 0 : 64;
    #pragma unroll
    for (int mi = 0; mi < 4; ++mi) {
        #pragma unroll
        for (int ni = 0; ni < 4; ++ni) {
            #pragma unroll
            for (int r = 0; r < 4; ++r) {
                const int m = r0 + mi * 16 + (lane >> 4) * 4 + r;
                const int n = c0 + ni * 16 + (lane & 15);
                if (m < 100) {
                    if (n < 100)      out[base + 1110 + m * 100 + n]         = acc[mi][ni][r];
                    else if (n < 110) out[base + 110  + m * 10  + (n - 100)] = acc[mi][ni][r];
                }
            }
        }
    }
}

extern "C" void kernel_launch(void* const* d_in, const int* in_sizes, int n_in,
                              void* d_out, int out_size, void* d_ws, size_t ws_size,
                              hipStream_t stream) {
    const float* x = (const float*)d_in[0];
    float* out = (float*)d_out;
    const int B = in_sizes[0] / 2560;   // 2048 batches, one block each
    sig_mfma10<<<B, 256, 0, stream>>>(x, out);
}